// Round 1
// baseline (486.418 us; speedup 1.0000x reference)
//
#include <hip/hip_runtime.h>
#include <math.h>

// Problem constants
#define NS      32768           // N_SAMPLES
#define M       16384           // NS/2, packed complex FFT length = 4^7
#define NEV     16
#define NB      64
#define T2      512             // threads for FFT kernels (8 waves)

// LDS padding: one extra float2 every 32 elements to spread banks
__device__ __forceinline__ int ldsIdx(int i) { return i + (i >> 5); }
#define LDS_ELEMS (M + M / 32)   // 16896 float2 = 135168 B < 160 KB

__device__ __forceinline__ float2 cmul(float2 a, float2 b) {
    return make_float2(a.x * b.x - a.y * b.y, a.x * b.y + a.y * b.x);
}

// reverse 7 base-4 digits (14 bits)
__device__ __forceinline__ int rev4_14(int i) {
    int r = 0;
#pragma unroll
    for (int d = 0; d < 7; ++d) { r = (r << 2) | (i & 3); i >>= 2; }
    return r;
}

// e^{-i*2*pi*k*s/NS}, s = si + sf (integer + fraction), exact integer mod
__device__ __forceinline__ float2 shift_phase(int k, int si, float sf) {
    unsigned ksi = ((unsigned)k * (unsigned)si) & (unsigned)(NS - 1);
    float total = (float)ksi + (float)k * sf;
    float f = total * (1.0f / (float)NS);
    f -= floorf(f);
    float ang = -6.28318530717958647692f * f;
    float sv, cv;
    __sincosf(ang, &sv, &cv);
    return make_float2(cv, sv);
}

// In-place complex FFT of M=4^7 points in LDS. SIGN=-1 forward (e^{-i}),
// SIGN=+1 inverse (e^{+i}, unscaled). tbl[j] = e^{-2*pi*i*j/M}.
template <int SIGN>
__device__ void fft_lds(float2* lds, const float2* __restrict__ tbl, int tid) {
    // digit-reversal permutation (each unordered pair swapped by owner of min idx)
    for (int i = tid; i < M; i += T2) {
        int r = rev4_14(i);
        if (r > i) {
            float2 a = lds[ldsIdx(i)];
            float2 b = lds[ldsIdx(r)];
            lds[ldsIdx(i)] = b;
            lds[ldsIdx(r)] = a;
        }
    }
    __syncthreads();
#pragma unroll
    for (int t = 0; t < 7; ++t) {
        const int q = 1 << (2 * t);
        const int tshift = 2 * (6 - t);
        for (int bf = tid; bf < M / 4; bf += T2) {
            const int g = bf >> (2 * t);
            const int j = bf & (q - 1);
            const int base = (g << (2 * t + 2)) + j;
            const int I0 = ldsIdx(base);
            const int I1 = ldsIdx(base + q);
            const int I2 = ldsIdx(base + 2 * q);
            const int I3 = ldsIdx(base + 3 * q);
            float2 w1 = tbl[j << tshift];
            if (SIGN > 0) w1.y = -w1.y;
            float2 w2 = cmul(w1, w1);
            float2 w3 = cmul(w2, w1);
            float2 a0 = lds[I0];
            float2 a1 = cmul(lds[I1], w1);
            float2 a2 = cmul(lds[I2], w2);
            float2 a3 = cmul(lds[I3], w3);
            float2 u0 = make_float2(a0.x + a2.x, a0.y + a2.y);
            float2 u1 = make_float2(a0.x - a2.x, a0.y - a2.y);
            float2 u2 = make_float2(a1.x + a3.x, a1.y + a3.y);
            float2 u3 = make_float2(a1.x - a3.x, a1.y - a3.y);
            lds[I0] = make_float2(u0.x + u2.x, u0.y + u2.y);
            lds[I2] = make_float2(u0.x - u2.x, u0.y - u2.y);
            if (SIGN < 0) {
                lds[I1] = make_float2(u1.x + u3.y, u1.y - u3.x);  // u1 - i*u3
                lds[I3] = make_float2(u1.x - u3.y, u1.y + u3.x);  // u1 + i*u3
            } else {
                lds[I1] = make_float2(u1.x - u3.y, u1.y + u3.x);
                lds[I3] = make_float2(u1.x + u3.y, u1.y - u3.x);
            }
        }
        __syncthreads();
    }
}

// e^{-i*pi/M} for odd-k half-step twiddle (w_N^k = tbl[k>>1] * (k&1 ? chalf : 1))
#define COS_HALF 0.99999998161642933f
#define SIN_HALF 1.91747597315173178e-4f

__global__ void twiddle_kernel(float2* __restrict__ tbl) {
    int j = blockIdx.x * blockDim.x + threadIdx.x;
    if (j < M) {
        float ang = -6.28318530717958647692f * ((float)j / (float)M);
        float sv, cv;
        sincosf(ang, &sv, &cv);
        tbl[j] = make_float2(cv, sv);
    }
}

// shifts[b*16+e] = sigmoid(dot(tl[b,e,:], W) + b0) * NS
__global__ __launch_bounds__(64) void pos_kernel(const float* __restrict__ tl,
                                                 const float* __restrict__ W,
                                                 const float* __restrict__ bp,
                                                 float* __restrict__ shifts) {
    int bid = blockIdx.x;
    int t = threadIdx.x;
    const float* row = tl + (size_t)bid * 128;
    float p = row[t] * W[t] + row[t + 64] * W[t + 64];
#pragma unroll
    for (int off = 32; off > 0; off >>= 1) p += __shfl_down(p, off);
    if (t == 0) {
        float x = p + bp[0];
        float sig = 1.0f / (1.0f + expf(-x));
        shifts[bid] = sig * (float)NS;
    }
}

// Forward: per (b,e): packed real FFT -> unpack rfft bins -> phase -> atomic acc.
// Accumulator layout in d_out (per batch, 16384 float2):
//   slot[0] = (A[0].re, A[M].re)   (DC and Nyquist, real parts only)
//   slot[k] = A[k] (complex), k=1..M-1
__global__ __launch_bounds__(T2) void fwd_kernel(const float* __restrict__ stems,
                                                 const float* __restrict__ shifts,
                                                 float* __restrict__ acc_base,
                                                 const float2* __restrict__ tbl) {
    __shared__ float2 lds[LDS_ELEMS];
    const int tid = threadIdx.x;
    // e-major swizzle: all 16 events of a batch land on same XCD (blockIdx % 8 heuristic)
    const int b = blockIdx.x & 63;
    const int e = blockIdx.x >> 6;
    const int row = b * NEV + e;

    const float4* src = (const float4*)(stems + (size_t)row * NS);
    for (int i = tid; i < NS / 4; i += T2) {
        float4 v = src[i];
        lds[ldsIdx(2 * i)] = make_float2(v.x, v.y);
        lds[ldsIdx(2 * i + 1)] = make_float2(v.z, v.w);
    }
    __syncthreads();

    fft_lds<-1>(lds, tbl, tid);

    const float s = shifts[row];
    const int si = (int)floorf(s);
    const float sf = s - (float)si;
    float2* acc = (float2*)acc_base + (size_t)b * M;
    const float2 chalf = make_float2(COS_HALF, -SIN_HALF);

    for (int k = tid; k < M; k += T2) {
        if (k == 0) {
            float2 z0 = lds[ldsIdx(0)];
            float X0 = z0.x + z0.y;   // DC, phase = 1
            float XM = z0.x - z0.y;   // Nyquist (real)
            float2 phM = shift_phase(M, si, sf);
            unsafeAtomicAdd(&acc[0].x, X0);
            unsafeAtomicAdd(&acc[0].y, XM * phM.x);  // only Re survives irfft
        } else {
            float2 Zk = lds[ldsIdx(k)];
            float2 Zr = lds[ldsIdx(M - k)];
            float2 E = make_float2(0.5f * (Zk.x + Zr.x), 0.5f * (Zk.y - Zr.y));
            float2 O = make_float2(0.5f * (Zk.y + Zr.y), -0.5f * (Zk.x - Zr.x));
            float2 w = tbl[k >> 1];
            if (k & 1) w = cmul(w, chalf);
            float2 wo = cmul(w, O);
            float2 X = make_float2(E.x + wo.x, E.y + wo.y);
            float2 ph = shift_phase(k, si, sf);
            float2 P = cmul(X, ph);
            unsafeAtomicAdd(&acc[k].x, P.x);
            unsafeAtomicAdd(&acc[k].y, P.y);
        }
    }
}

// Inverse: per batch: rebuild packed spectrum Z' from accumulated rfft bins,
// inverse CFFT, write real output (overwrites the accumulator region).
__global__ __launch_bounds__(T2) void inv_kernel(float* __restrict__ out,
                                                 const float2* __restrict__ tbl) {
    __shared__ float2 lds[LDS_ELEMS];
    const int tid = threadIdx.x;
    const int b = blockIdx.x;
    float2* acc = (float2*)out + (size_t)b * M;

    const float4* src = (const float4*)acc;
    for (int i = tid; i < M / 2; i += T2) {
        float4 v = src[i];
        lds[ldsIdx(2 * i)] = make_float2(v.x, v.y);
        lds[ldsIdx(2 * i + 1)] = make_float2(v.z, v.w);
    }
    __syncthreads();

    const float2 chalf = make_float2(COS_HALF, -SIN_HALF);
    for (int k = tid; k < M / 2; k += T2) {
        if (k == 0) {
            float2 a0 = lds[ldsIdx(0)];  // (A0.re, AM.re)
            lds[ldsIdx(0)] = make_float2(0.5f * (a0.x + a0.y), 0.5f * (a0.x - a0.y));
            float2 ah = lds[ldsIdx(M / 2)];
            lds[ldsIdx(M / 2)] = make_float2(ah.x, -ah.y);  // Z'[M/2] = conj(A[M/2])
        } else {
            float2 a = lds[ldsIdx(k)];
            float2 bb = lds[ldsIdx(M - k)];
            float2 w = tbl[k >> 1];
            if (k & 1) w = cmul(w, chalf);
            // Z'[k] = E + i*O, E = (A[k]+conj(A[M-k]))/2, O = conj(w)*(A[k]-conj(A[M-k]))/2
            float2 E1 = make_float2(0.5f * (a.x + bb.x), 0.5f * (a.y - bb.y));
            float2 D1 = make_float2(0.5f * (a.x - bb.x), 0.5f * (a.y + bb.y));
            float2 wc = make_float2(w.x, -w.y);
            float2 O1 = cmul(wc, D1);
            float2 z1 = make_float2(E1.x - O1.y, E1.y + O1.x);
            // Z'[M-k]: E2 = (E1.x, -E1.y), D2 = (-D1.x, D1.y), O2 = -w*D2
            float2 E2 = make_float2(E1.x, -E1.y);
            float2 D2 = make_float2(-D1.x, D1.y);
            float2 O2 = cmul(w, D2);
            O2 = make_float2(-O2.x, -O2.y);
            float2 z2 = make_float2(E2.x - O2.y, E2.y + O2.x);
            lds[ldsIdx(k)] = z1;
            lds[ldsIdx(M - k)] = z2;
        }
    }
    __syncthreads();

    fft_lds<1>(lds, tbl, tid);

    const float invM = 1.0f / (float)M;
    float4* dst = (float4*)(out + (size_t)b * NS);
    for (int i = tid; i < NS / 4; i += T2) {
        float2 z0 = lds[ldsIdx(2 * i)];
        float2 z1 = lds[ldsIdx(2 * i + 1)];
        dst[i] = make_float4(z0.x * invM, z0.y * invM, z1.x * invM, z1.y * invM);
    }
}

extern "C" void kernel_launch(void* const* d_in, const int* in_sizes, int n_in,
                              void* d_out, int out_size, void* d_ws, size_t ws_size,
                              hipStream_t stream) {
    const float* time_latent = (const float*)d_in[0];
    const float* stems = (const float*)d_in[1];
    // d_in[2] = targets: unused by the reference output
    const float* W_pos = (const float*)d_in[3];
    const float* b_pos = (const float*)d_in[4];
    float* out = (float*)d_out;

    float2* tbl = (float2*)d_ws;                                   // 128 KB
    float* shifts = (float*)((char*)d_ws + (size_t)M * sizeof(float2));  // 4 KB

    // d_out doubles as the spectral accumulator: zero it first
    hipMemsetAsync(d_out, 0, (size_t)out_size * sizeof(float), stream);

    twiddle_kernel<<<M / 256, 256, 0, stream>>>(tbl);
    pos_kernel<<<NB * NEV, 64, 0, stream>>>(time_latent, W_pos, b_pos, shifts);
    fwd_kernel<<<NB * NEV, T2, 0, stream>>>(stems, shifts, out, tbl);
    inv_kernel<<<NB, T2, 0, stream>>>(out, tbl);
}